// Round 10
// baseline (552.481 us; speedup 1.0000x reference)
//
#include <hip/hip_runtime.h>
#include <hip/hip_bf16.h>
#include <math.h>

#define CHANNELS 64
#define KK 25                   // 5x5 kernels
#define NBLK 26                 // 25 spline kernels + 1 root block
#define NCOL (NBLK * CHANNELS)  // 1664 columns of the fused GEMM
#define NTILES (NCOL / 16)      // 104 col-tiles of 16
#define ROWB (NCOL * 2)         // 3328 bytes per xk row
#define GROUP_TILES 8
#define GROUP_BYTES (GROUP_TILES * 2048)  // 16 KB per staged group
#define NGROUPS (NTILES / GROUP_TILES)    // 13 (exact)
#define G_SPLIT 6               // L1 gemm split: groups [0,6) + [6,13)

typedef __attribute__((ext_vector_type(8))) short bf16x8;
typedef __attribute__((ext_vector_type(4))) float f32x4;
typedef unsigned int u32;

// RNE float -> bf16 bits
__device__ __forceinline__ u32 f2bfu(float f) {
    u32 u = __float_as_uint(f);
    return (u + 0x7FFFu + ((u >> 16) & 1u)) >> 16;
}
__device__ __forceinline__ short f2bf(float f) { return (short)f2bfu(f); }
// unpack packed bf16 pair (u32) -> floats
__device__ __forceinline__ float blo(u32 u) { return __uint_as_float(u << 16); }
__device__ __forceinline__ float bhi(u32 u) { return __uint_as_float(u & 0xffff0000u); }

// async global->LDS, 16 B per lane (lds dest = wave-uniform base + lane*16)
__device__ __forceinline__ void async_copy16(const void* g, void* l) {
    __builtin_amdgcn_global_load_lds(
        (const __attribute__((address_space(1))) u32*)g,
        (__attribute__((address_space(3))) u32*)l, 16, 0, 0);
}

// ---------------- CSR scan kernels ----------------

// A: per-block (1024 items) sums
__global__ __launch_bounds__(256) void scan_a(const u32* __restrict__ counts,
                                              u32* __restrict__ bsum, int N) {
    const int t = threadIdx.x;
    const int base = blockIdx.x * 1024 + t * 4;
    uint4 v = make_uint4(0, 0, 0, 0);
    if (base + 3 < N) v = *(const uint4*)(counts + base);
    else {
        if (base < N)     v.x = counts[base];
        if (base + 1 < N) v.y = counts[base + 1];
        if (base + 2 < N) v.z = counts[base + 2];
    }
    u32 s = v.x + v.y + v.z + v.w;
    for (int off = 32; off; off >>= 1) s += __shfl_down(s, off, 64);
    __shared__ u32 red[4];
    if ((t & 63) == 0) red[t >> 6] = s;
    __syncthreads();
    if (t == 0) bsum[blockIdx.x] = red[0] + red[1] + red[2] + red[3];
}

// B: single-wave exclusive scan of bsum[nb]
__global__ __launch_bounds__(64) void scan_b(u32* __restrict__ bsum, int nb) {
    const int lane = threadIdx.x;
    u32 run = 0;
    for (int base = 0; base < nb; base += 64) {
        u32 v = (base + lane < nb) ? bsum[base + lane] : 0u;
        const u32 orig = v;
        for (int off = 1; off < 64; off <<= 1) {
            u32 u = __shfl_up(v, off, 64);
            if (lane >= off) v += u;
        }
        if (base + lane < nb) bsum[base + lane] = run + v - orig;
        run += __shfl(v, 63, 64);
    }
}

// C: exclusive prefix -> cursor[0..N-1]; also cursor[N] = total (=E)
__global__ __launch_bounds__(256) void scan_c(const u32* __restrict__ counts,
                                              const u32* __restrict__ bsum,
                                              u32* __restrict__ cursor, int N) {
    const int t = threadIdx.x;
    const int base = blockIdx.x * 1024 + t * 4;
    uint4 v = make_uint4(0, 0, 0, 0);
    if (base + 3 < N) v = *(const uint4*)(counts + base);
    else {
        if (base < N)     v.x = counts[base];
        if (base + 1 < N) v.y = counts[base + 1];
        if (base + 2 < N) v.z = counts[base + 2];
    }
    __shared__ u32 ps[256];
    ps[t] = v.x + v.y + v.z + v.w;
    __syncthreads();
    for (int off = 1; off < 256; off <<= 1) {
        u32 u = (t >= off) ? ps[t - off] : 0u;
        __syncthreads();
        ps[t] += u;
        __syncthreads();
    }
    u32 ex = ((t > 0) ? ps[t - 1] : 0u) + bsum[blockIdx.x];
    if (base < N)     cursor[base]     = ex;
    if (base + 1 < N) cursor[base + 1] = ex + v.x;
    if (base + 2 < N) cursor[base + 2] = ex + v.x + v.y;
    if (base + 3 < N) cursor[base + 3] = ex + v.x + v.y + v.z;
    if (base <= N - 1 && N - 1 <= base + 3)
        cursor[N] = ex + v.x + v.y + v.z + v.w;
}

// ---------------- gemm body (LDS-staged MFMA, swapped operands) ----------------

// Repack [W | root] fp32 -> Wb bf16 fragment order (lane&15 = col-in-tile,
// k = q*32 + (lane>>4)*8 + j). A- and B-fragment layouts are symmetric, so this
// packing serves the W fragment in either MFMA operand role.
__global__ __launch_bounds__(256) void prep_w(const float* __restrict__ W,
                                              const float* __restrict__ root,
                                              __hip_bfloat16* __restrict__ Wb) {
    int idx = blockIdx.x * 256 + threadIdx.x;   // 104*2*64*8 = 106496
    if (idx >= NTILES * 2 * 64 * 8) return;
    int j = idx & 7;
    int l = (idx >> 3) & 63;
    int q = (idx >> 9) & 1;
    int t = idx >> 10;
    int col  = t * 16 + (l & 15);
    int k    = q * 32 + (l >> 4) * 8 + j;
    int kk   = col >> 6;
    int o    = col & 63;
    float src = (kk < KK) ? W[kk * 4096 + k * 64 + o] : root[k * 64 + o];
    ((unsigned short*)Wb)[idx] = (unsigned short)f2bf(src);
}

// XK[n, c] = sum_i X[n,i] * B[i,c] over column groups [gr0, gr1).
// Wb double-buffer staged into LDS. MFMA operands SWAPPED (A = W cols, B = X
// rows): lane holds 4 CONSECUTIVE xk cols of node rb+(lane&15) -> single packed
// 8 B store per tile (104 stores/wave instead of 416). Store form proven in R5.
__device__ __forceinline__ void gemm_body(
    const float* __restrict__ X, const __hip_bfloat16* __restrict__ Wb,
    __hip_bfloat16* __restrict__ XK, int N, int gr0, int gr1)
{
    __shared__ __align__(16) char lds[2][GROUP_BYTES];
    const int lane = threadIdx.x & 63;
    const int wv   = threadIdx.x >> 6;
    const int rb   = blockIdx.x * 64 + wv * 16;
    const int m    = lane & 15;
    const int quad = lane >> 4;

    // X fragment (B operand): lane holds X[rb+m][k = q*32 + quad*8 + j]
    const int rowc = min(rb + m, N - 1);
    const float* __restrict__ xp = X + (size_t)rowc * CHANNELS + quad * 8;
    float af[16];
    *(float4*)(af)      = *(const float4*)(xp);
    *(float4*)(af + 4)  = *(const float4*)(xp + 4);
    *(float4*)(af + 8)  = *(const float4*)(xp + 32);
    *(float4*)(af + 12) = *(const float4*)(xp + 36);
    bf16x8 Xf0, Xf1;
#pragma unroll
    for (int j = 0; j < 8; ++j) { Xf0[j] = f2bf(af[j]); Xf1[j] = f2bf(af[8 + j]); }

    // store: node = rb + m (row), cols t*16 + quad*4 .. +3 packed into 8 B
    const int node = rb + m;
    const bool wr = node < N;
    char* __restrict__ outp = (char*)XK + (size_t)node * ROWB + quad * 8;

    const char* __restrict__ wbc = (const char*)Wb;
#define STAGE(g, buf)                                                          \
    {                                                                          \
        const char* gsrc = wbc + (size_t)(g) * GROUP_BYTES + wv * 4096 + lane * 16; \
        char* lbase = lds[buf] + wv * 4096;                                    \
        async_copy16(gsrc,        lbase);                                      \
        async_copy16(gsrc + 1024, lbase + 1024);                               \
        async_copy16(gsrc + 2048, lbase + 2048);                               \
        async_copy16(gsrc + 3072, lbase + 3072);                               \
    }

    STAGE(gr0, 0)
    for (int g = gr0; g < gr1; ++g) {
        const int li = (g - gr0) & 1;
        __syncthreads();           // drains staged loads for g
        if (g + 1 < gr1) STAGE(g + 1, li ^ 1)
        const char* lb = lds[li] + lane * 16;
#pragma unroll
        for (int tt = 0; tt < GROUP_TILES; ++tt) {
            bf16x8 Wf0 = *(const bf16x8*)(lb + tt * 2048);
            bf16x8 Wf1 = *(const bf16x8*)(lb + tt * 2048 + 1024);
            f32x4 acc = {0.f, 0.f, 0.f, 0.f};
            acc = __builtin_amdgcn_mfma_f32_16x16x32_bf16(Wf0, Xf0, acc, 0, 0, 0);
            acc = __builtin_amdgcn_mfma_f32_16x16x32_bf16(Wf1, Xf1, acc, 0, 0, 0);
            const int t = g * GROUP_TILES + tt;
            if (wr) {
                uint2 p;
                p.x = f2bfu(acc[0]) | (f2bfu(acc[1]) << 16);
                p.y = f2bfu(acc[2]) | (f2bfu(acc[3]) << 16);
                *(uint2*)(outp + t * 32) = p;
            }
        }
    }
#undef STAGE
}

// fusedA: blocks < gemm_blocks run gemm on groups [0, G_SPLIT);
// the rest run the dst histogram with rank capture (CSR-independent of gemm).
__global__ __launch_bounds__(256) void gemm_hist(
    const float* __restrict__ X, const __hip_bfloat16* __restrict__ Wb,
    __hip_bfloat16* __restrict__ XK, int N, int gemm_blocks,
    const int* __restrict__ ei, u32* __restrict__ counts,
    u32* __restrict__ rank, int E)
{
    if ((int)blockIdx.x >= gemm_blocks) {
        int e = ((int)blockIdx.x - gemm_blocks) * 256 + threadIdx.x;
        if (e < E) rank[e] = atomicAdd(&counts[ei[E + e]], 1u);
        return;
    }
    gemm_body(X, Wb, XK, N, 0, G_SPLIT);
}

// fusedB: blocks < gemm_blocks run gemm on groups [gr0, gr1);
// the rest scatter 8 B edge records (atomic-free: cursor[dst] + rank[e]).
__global__ __launch_bounds__(256) void gemm_scatter(
    const float* __restrict__ X, const __hip_bfloat16* __restrict__ Wb,
    __hip_bfloat16* __restrict__ XK, int N, int gemm_blocks,
    const int* __restrict__ ei, const float* __restrict__ ps,
    const u32* __restrict__ rank, const u32* __restrict__ cursor,
    uint2* __restrict__ sorted, int E, int gr0, int gr1)
{
    if ((int)blockIdx.x >= gemm_blocks) {
        int e = ((int)blockIdx.x - gemm_blocks) * 256 + threadIdx.x;
        if (e >= E) return;
        const int src = ei[e];
        const int dst = ei[E + e];
        const float v0 = ps[2 * e]     * 4.0f;
        const float v1 = ps[2 * e + 1] * 4.0f;
        const float fb0 = floorf(v0), fb1 = floorf(v1);
        const float f0 = v0 - fb0, f1 = v1 - fb1;
        const int b0 = max(min((int)fb0, 4), 0);
        const int b1 = max(min((int)fb1, 4), 0);
        const u32 f0q = (u32)(f0 * 65536.0f);
        const u32 f1q = (u32)(f1 * 65536.0f);
        uint2 rec;
        rec.x = (u32)src | ((u32)b0 << 16) | ((u32)b1 << 19);
        rec.y = f0q | (f1q << 16);
        sorted[cursor[dst] + rank[e]] = rec;
        return;
    }
    gemm_body(X, Wb, XK, N, gr0, gr1);
}

// ------------- fused segment-max + root + bias (+relu): 4 edges / wave-iter -------------
// R8-proven form: quarter q = lane>>4 handles edge i+q, sublane j = lane&15 handles
// channels 4j..4j+3 (8 B gathers); 2-deep software pipeline. 8 B records:
// x = src | b0<<16 | b1<<19 ; y = f0q16 | f1q16<<16 (fixed point /65536).
__global__ __launch_bounds__(256) void agg_node(
    const uint2* __restrict__ sorted, const u32* __restrict__ cursor,
    const __hip_bfloat16* __restrict__ XK, const float* __restrict__ bias,
    float* __restrict__ out, int N, int do_relu)
{
    const int lane = threadIdx.x & 63;
    const int n = blockIdx.x * 4 + (threadIdx.x >> 6);
    if (n >= N) return;
    const int q = lane >> 4, j = lane & 15;
    const int beg = (int)cursor[n];
    const int end = (int)cursor[n + 1];

    float m0 = -INFINITY, m1 = -INFINITY, m2 = -INFINITY, m3 = -INFINITY;
    if (beg < end) {
        const int last = end - 1;
        uint2 rA = sorted[min(beg + q, last)];
        uint2 rB = sorted[min(beg + 4 + q, last)];
        const char* baseA = (const char*)XK + (size_t)(rA.x & 0xffff) * ROWB + (j << 3);
        int oA = ((int)((rA.x >> 16) & 7) + 5 * (int)((rA.x >> 19) & 7)) << 7;
        uint2 g0 = *(const uint2*)(baseA + oA);
        uint2 g1 = *(const uint2*)(baseA + oA + 128);
        uint2 g2 = *(const uint2*)(baseA + oA + 640);
        uint2 g3 = *(const uint2*)(baseA + oA + 768);
        for (int i = beg; i < end; i += 4) {
            uint2 rC = sorted[min(i + 8 + q, last)];
            const char* baseB = (const char*)XK + (size_t)(rB.x & 0xffff) * ROWB + (j << 3);
            int oB = ((int)((rB.x >> 16) & 7) + 5 * (int)((rB.x >> 19) & 7)) << 7;
            uint2 h0 = *(const uint2*)(baseB + oB);
            uint2 h1 = *(const uint2*)(baseB + oB + 128);
            uint2 h2 = *(const uint2*)(baseB + oB + 640);
            uint2 h3 = *(const uint2*)(baseB + oB + 768);
            const float f0 = (float)(rA.y & 0xffff) * (1.0f / 65536.0f);
            const float f1 = (float)(rA.y >> 16)    * (1.0f / 65536.0f);
            const float w00 = (1.f - f0) * (1.f - f1);
            const float w10 = f0 * (1.f - f1);
            const float w01 = (1.f - f0) * f1;
            const float w11 = f0 * f1;
            float v0 = fmaf(blo(g3.x), w11, fmaf(blo(g2.x), w01, fmaf(blo(g1.x), w10, blo(g0.x) * w00)));
            float v1 = fmaf(bhi(g3.x), w11, fmaf(bhi(g2.x), w01, fmaf(bhi(g1.x), w10, bhi(g0.x) * w00)));
            float v2 = fmaf(blo(g3.y), w11, fmaf(blo(g2.y), w01, fmaf(blo(g1.y), w10, blo(g0.y) * w00)));
            float v3 = fmaf(bhi(g3.y), w11, fmaf(bhi(g2.y), w01, fmaf(bhi(g1.y), w10, bhi(g0.y) * w00)));
            m0 = fmaxf(m0, v0); m1 = fmaxf(m1, v1);
            m2 = fmaxf(m2, v2); m3 = fmaxf(m3, v3);
            rA = rB; rB = rC;
            g0 = h0; g1 = h1; g2 = h2; g3 = h3;
        }
    }
    m0 = fmaxf(m0, __shfl_xor(m0, 16, 64)); m0 = fmaxf(m0, __shfl_xor(m0, 32, 64));
    m1 = fmaxf(m1, __shfl_xor(m1, 16, 64)); m1 = fmaxf(m1, __shfl_xor(m1, 32, 64));
    m2 = fmaxf(m2, __shfl_xor(m2, 16, 64)); m2 = fmaxf(m2, __shfl_xor(m2, 32, 64));
    m3 = fmaxf(m3, __shfl_xor(m3, 16, 64)); m3 = fmaxf(m3, __shfl_xor(m3, 32, 64));
    const float a0 = isfinite(m0) ? m0 : 0.f;
    const float a1 = isfinite(m1) ? m1 : 0.f;
    const float a2 = isfinite(m2) ? m2 : 0.f;
    const float a3 = isfinite(m3) ? m3 : 0.f;

    const uint2 rt = *(const uint2*)((const char*)XK + (size_t)(unsigned)n * ROWB
                                     + KK * 128 + (j << 3));
    const float4 bv = *(const float4*)(bias + 4 * j);
    float r0 = a0 + blo(rt.x) + bv.x;
    float r1 = a1 + bhi(rt.x) + bv.y;
    float r2 = a2 + blo(rt.y) + bv.z;
    float r3 = a3 + bhi(rt.y) + bv.w;
    if (do_relu) {
        r0 = fmaxf(r0, 0.f); r1 = fmaxf(r1, 0.f);
        r2 = fmaxf(r2, 0.f); r3 = fmaxf(r3, 0.f);
    }
    if (q == 0)
        *(float4*)(out + (size_t)n * CHANNELS + 4 * j) = make_float4(r0, r1, r2, r3);
}

extern "C" void kernel_launch(void* const* d_in, const int* in_sizes, int n_in,
                              void* d_out, int out_size, void* d_ws, size_t ws_size,
                              hipStream_t stream) {
    const float* x     = (const float*)d_in[0];
    const int*   ei    = (const int*)d_in[1];
    const float* ps    = (const float*)d_in[2];
    const float* W1    = (const float*)d_in[3];
    const float* root1 = (const float*)d_in[4];
    const float* bias1 = (const float*)d_in[5];
    const float* W2    = (const float*)d_in[6];
    const float* root2 = (const float*)d_in[7];
    const float* bias2 = (const float*)d_in[8];
    float* out = (float*)d_out;

    const int N = in_sizes[0] / CHANNELS;
    const int E = in_sizes[1] / 2;

    // ---- workspace layout (~199 MB) ----
    char* ws = (char*)d_ws;
    __hip_bfloat16* xk = (__hip_bfloat16*)ws;                       // N*1664*2 = 166.4 MB
    size_t off = (size_t)N * NCOL * sizeof(__hip_bfloat16);
    float* h = (float*)(ws + off);                                  // 12.8 MB
    off += (size_t)N * CHANNELS * sizeof(float);
    uint2* sorted = (uint2*)(ws + off);                             // E*8 = 12.8 MB
    off += (size_t)E * sizeof(uint2);
    u32* rank = (u32*)(ws + off);                                   // E*4 = 6.4 MB
    off += (size_t)E * sizeof(u32);
    u32* counts = (u32*)(ws + off);                                 // N*4 (hist runs under gemm)
    off += (size_t)N * 4;
    __hip_bfloat16* Wb = (__hip_bfloat16*)(ws + off);               // 213 KB
    off += (size_t)NTILES * 2 * 64 * 8 * 2;
    u32* cursor = (u32*)(ws + off);                                 // (N+1)*4
    off += ((size_t)N + 1) * 4;
    u32* bsum = (u32*)(ws + off);                                   // ≤4 KB

    const int prep_blocks = (NTILES * 2 * 64 * 8 + 255) / 256;
    const int gemm_blocks = (N + 63) / 64;
    const int node_blocks = (N + 3) / 4;
    const int edgeT_blocks = (E + 255) / 256;
    const int scan_blocks = (N + 1023) / 1024;

    // zero the histogram (capture-safe async memset)
    hipMemsetAsync(counts, 0, (size_t)N * 4, stream);
    prep_w<<<prep_blocks, 256, 0, stream>>>(W1, root1, Wb);

    // fusedA: L1 gemm groups [0,6) || dst-histogram with rank capture
    gemm_hist<<<gemm_blocks + edgeT_blocks, 256, 0, stream>>>(
        x, Wb, xk, N, gemm_blocks, ei, counts, rank, E);

    scan_a<<<scan_blocks, 256, 0, stream>>>(counts, bsum, N);
    scan_b<<<1, 64, 0, stream>>>(bsum, scan_blocks);
    scan_c<<<scan_blocks, 256, 0, stream>>>(counts, bsum, cursor, N);

    // fusedB: L1 gemm groups [6,13) || CSR scatter (atomic-free)
    gemm_scatter<<<gemm_blocks + edgeT_blocks, 256, 0, stream>>>(
        x, Wb, xk, N, gemm_blocks, ei, ps, rank, cursor, sorted, E, G_SPLIT, NGROUPS);
    agg_node<<<node_blocks, 256, 0, stream>>>(sorted, cursor, xk, bias1, h, N, 1);

    // ---- layer 2 ----
    prep_w<<<prep_blocks, 256, 0, stream>>>(W2, root2, Wb);
    gemm_scatter<<<gemm_blocks, 256, 0, stream>>>(
        h, Wb, xk, N, gemm_blocks, ei, ps, rank, cursor, sorted, 0, 0, NGROUPS);
    agg_node<<<node_blocks, 256, 0, stream>>>(sorted, cursor, xk, bias2, out, N, 0);
}

// Round 11
// 491.211 us; speedup vs baseline: 1.1247x; 1.1247x over previous
//
#include <hip/hip_runtime.h>
#include <hip/hip_bf16.h>
#include <math.h>

#define CHANNELS 64
#define KK 25                   // 5x5 kernels
#define NBLK 26                 // 25 spline kernels + 1 root block
#define NCOL (NBLK * CHANNELS)  // 1664 columns of the fused GEMM
#define NTILES (NCOL / 16)      // 104 col-tiles of 16
#define ROWB2 (NCOL * 2)        // 3328 B per xk row, bf16 layout (layer 2)
#define ROWB1 1728              // fp8 layout (layer 1): 25*64 fp8 + 128 B bf16 root
#define GROUP_TILES 8
#define GROUP_BYTES (GROUP_TILES * 2048)  // 16 KB per staged group
#define NGROUPS (NTILES / GROUP_TILES)    // 13 (exact)
#define G_SPLIT 6               // L1 gemm split: groups [0,6) + [6,13)

typedef __attribute__((ext_vector_type(8))) short bf16x8;
typedef __attribute__((ext_vector_type(4))) float f32x4;
typedef unsigned int u32;

// RNE float -> bf16 bits
__device__ __forceinline__ u32 f2bfu(float f) {
    u32 u = __float_as_uint(f);
    return (u + 0x7FFFu + ((u >> 16) & 1u)) >> 16;
}
__device__ __forceinline__ short f2bf(float f) { return (short)f2bfu(f); }
// unpack packed bf16 pair (u32) -> floats
__device__ __forceinline__ float blo(u32 u) { return __uint_as_float(u << 16); }
__device__ __forceinline__ float bhi(u32 u) { return __uint_as_float(u & 0xffff0000u); }
// f32 -> fp8 e4m3 (OCP on gfx950), one byte
__device__ __forceinline__ unsigned char f2fp8(float f) {
    return (unsigned char)(__builtin_amdgcn_cvt_pk_fp8_f32(f, f, 0, false) & 0xff);
}

// async global->LDS, 16 B per lane (lds dest = wave-uniform base + lane*16)
__device__ __forceinline__ void async_copy16(const void* g, void* l) {
    __builtin_amdgcn_global_load_lds(
        (const __attribute__((address_space(1))) u32*)g,
        (__attribute__((address_space(3))) u32*)l, 16, 0, 0);
}

// ---------------- CSR scan kernels ----------------

__global__ __launch_bounds__(256) void scan_a(const u32* __restrict__ counts,
                                              u32* __restrict__ bsum, int N) {
    const int t = threadIdx.x;
    const int base = blockIdx.x * 1024 + t * 4;
    uint4 v = make_uint4(0, 0, 0, 0);
    if (base + 3 < N) v = *(const uint4*)(counts + base);
    else {
        if (base < N)     v.x = counts[base];
        if (base + 1 < N) v.y = counts[base + 1];
        if (base + 2 < N) v.z = counts[base + 2];
    }
    u32 s = v.x + v.y + v.z + v.w;
    for (int off = 32; off; off >>= 1) s += __shfl_down(s, off, 64);
    __shared__ u32 red[4];
    if ((t & 63) == 0) red[t >> 6] = s;
    __syncthreads();
    if (t == 0) bsum[blockIdx.x] = red[0] + red[1] + red[2] + red[3];
}

__global__ __launch_bounds__(64) void scan_b(u32* __restrict__ bsum, int nb) {
    const int lane = threadIdx.x;
    u32 run = 0;
    for (int base = 0; base < nb; base += 64) {
        u32 v = (base + lane < nb) ? bsum[base + lane] : 0u;
        const u32 orig = v;
        for (int off = 1; off < 64; off <<= 1) {
            u32 u = __shfl_up(v, off, 64);
            if (lane >= off) v += u;
        }
        if (base + lane < nb) bsum[base + lane] = run + v - orig;
        run += __shfl(v, 63, 64);
    }
}

__global__ __launch_bounds__(256) void scan_c(const u32* __restrict__ counts,
                                              const u32* __restrict__ bsum,
                                              u32* __restrict__ cursor, int N) {
    const int t = threadIdx.x;
    const int base = blockIdx.x * 1024 + t * 4;
    uint4 v = make_uint4(0, 0, 0, 0);
    if (base + 3 < N) v = *(const uint4*)(counts + base);
    else {
        if (base < N)     v.x = counts[base];
        if (base + 1 < N) v.y = counts[base + 1];
        if (base + 2 < N) v.z = counts[base + 2];
    }
    __shared__ u32 ps[256];
    ps[t] = v.x + v.y + v.z + v.w;
    __syncthreads();
    for (int off = 1; off < 256; off <<= 1) {
        u32 u = (t >= off) ? ps[t - off] : 0u;
        __syncthreads();
        ps[t] += u;
        __syncthreads();
    }
    u32 ex = ((t > 0) ? ps[t - 1] : 0u) + bsum[blockIdx.x];
    if (base < N)     cursor[base]     = ex;
    if (base + 1 < N) cursor[base + 1] = ex + v.x;
    if (base + 2 < N) cursor[base + 2] = ex + v.x + v.y;
    if (base + 3 < N) cursor[base + 3] = ex + v.x + v.y + v.z;
    if (base <= N - 1 && N - 1 <= base + 3)
        cursor[N] = ex + v.x + v.y + v.z + v.w;
}

// ---------------- gemm body (LDS-staged MFMA, R8-proven non-swapped form) ----------------

// Repack [W | root] fp32 -> Wb bf16 in B-fragment order.
__global__ __launch_bounds__(256) void prep_w(const float* __restrict__ W,
                                              const float* __restrict__ root,
                                              __hip_bfloat16* __restrict__ Wb) {
    int idx = blockIdx.x * 256 + threadIdx.x;   // 104*2*64*8 = 106496
    if (idx >= NTILES * 2 * 64 * 8) return;
    int j = idx & 7;
    int l = (idx >> 3) & 63;
    int q = (idx >> 9) & 1;
    int t = idx >> 10;
    int col  = t * 16 + (l & 15);
    int k    = q * 32 + (l >> 4) * 8 + j;
    int kk   = col >> 6;
    int o    = col & 63;
    float src = (kk < KK) ? W[kk * 4096 + k * 64 + o] : root[k * 64 + o];
    ((unsigned short*)Wb)[idx] = (unsigned short)f2bf(src);
}

// XK[n, c] = sum_i X[n,i] * B[i,c] over column groups [gr0, gr1).
// fp8out=1 (layer 1): spline tiles (t<100) stored fp8 e4m3, root tiles bf16,
// row stride ROWB1. fp8out=0 (layer 2): all bf16, row stride ROWB2.
__device__ __forceinline__ void gemm_body(
    const float* __restrict__ X, const __hip_bfloat16* __restrict__ Wb,
    char* __restrict__ XK, int N, int gr0, int gr1, int fp8out)
{
    __shared__ __align__(16) char lds[2][GROUP_BYTES];
    const int lane = threadIdx.x & 63;
    const int wv   = threadIdx.x >> 6;
    const int rb   = blockIdx.x * 64 + wv * 16;
    const int m    = lane & 15;
    const int quad = lane >> 4;

    const int rowc = min(rb + m, N - 1);
    const float* __restrict__ xp = X + (size_t)rowc * CHANNELS + quad * 8;
    float af[16];
    *(float4*)(af)      = *(const float4*)(xp);
    *(float4*)(af + 4)  = *(const float4*)(xp + 4);
    *(float4*)(af + 8)  = *(const float4*)(xp + 32);
    *(float4*)(af + 12) = *(const float4*)(xp + 36);
    bf16x8 A0, A1;
#pragma unroll
    for (int j = 0; j < 8; ++j) { A0[j] = f2bf(af[j]); A1[j] = f2bf(af[8 + j]); }

    const int r0 = rb + quad * 4;
    const int rmax = N - r0;
    const size_t rowb = fp8out ? (size_t)ROWB1 : (size_t)ROWB2;
    char* __restrict__ orow0 = XK + (size_t)r0 * rowb;

    const char* __restrict__ wbc = (const char*)Wb;
#define STAGE(g, buf)                                                          \
    {                                                                          \
        const char* gsrc = wbc + (size_t)(g) * GROUP_BYTES + wv * 4096 + lane * 16; \
        char* lbase = lds[buf] + wv * 4096;                                    \
        async_copy16(gsrc,        lbase);                                      \
        async_copy16(gsrc + 1024, lbase + 1024);                               \
        async_copy16(gsrc + 2048, lbase + 2048);                               \
        async_copy16(gsrc + 3072, lbase + 3072);                               \
    }

    STAGE(gr0, 0)
    for (int g = gr0; g < gr1; ++g) {
        const int li = (g - gr0) & 1;
        __syncthreads();           // drains staged loads for g
        if (g + 1 < gr1) STAGE(g + 1, li ^ 1)
        const char* lb = lds[li] + lane * 16;
#pragma unroll
        for (int tt = 0; tt < GROUP_TILES; ++tt) {
            bf16x8 B0 = *(const bf16x8*)(lb + tt * 2048);
            bf16x8 B1 = *(const bf16x8*)(lb + tt * 2048 + 1024);
            f32x4 acc = {0.f, 0.f, 0.f, 0.f};
            acc = __builtin_amdgcn_mfma_f32_16x16x32_bf16(A0, B0, acc, 0, 0, 0);
            acc = __builtin_amdgcn_mfma_f32_16x16x32_bf16(A1, B1, acc, 0, 0, 0);
            const int t = g * GROUP_TILES + tt;
#pragma unroll
            for (int i = 0; i < 4; ++i) {
                if (i < rmax) {
                    char* orow = orow0 + (size_t)i * rowb;
                    if (!fp8out) {
                        *(unsigned short*)(orow + (t * 16 + m) * 2) =
                            (unsigned short)f2bf(acc[i]);
                    } else if (t < 100) {
                        *(unsigned char*)(orow + t * 16 + m) = f2fp8(acc[i]);
                    } else {
                        *(unsigned short*)(orow + 1600 + (t - 100) * 32 + 2 * m) =
                            (unsigned short)f2bf(acc[i]);
                    }
                }
            }
        }
    }
#undef STAGE
}

// fusedA: blocks < gemm_blocks run gemm on groups [0, G_SPLIT);
// the rest run the dst histogram with rank capture (CSR-independent of gemm).
__global__ __launch_bounds__(256) void gemm_hist(
    const float* __restrict__ X, const __hip_bfloat16* __restrict__ Wb,
    char* __restrict__ XK, int N, int gemm_blocks, int fp8out,
    const int* __restrict__ ei, u32* __restrict__ counts,
    u32* __restrict__ rank, int E)
{
    if ((int)blockIdx.x >= gemm_blocks) {
        int e = ((int)blockIdx.x - gemm_blocks) * 256 + threadIdx.x;
        if (e < E) rank[e] = atomicAdd(&counts[ei[E + e]], 1u);
        return;
    }
    gemm_body(X, Wb, XK, N, 0, G_SPLIT, fp8out);
}

// fusedB: blocks < gemm_blocks run gemm on groups [gr0, gr1);
// the rest scatter 8 B edge records (atomic-free: cursor[dst] + rank[e]).
__global__ __launch_bounds__(256) void gemm_scatter(
    const float* __restrict__ X, const __hip_bfloat16* __restrict__ Wb,
    char* __restrict__ XK, int N, int gemm_blocks, int fp8out,
    const int* __restrict__ ei, const float* __restrict__ ps,
    const u32* __restrict__ rank, const u32* __restrict__ cursor,
    uint2* __restrict__ sorted, int E, int gr0, int gr1)
{
    if ((int)blockIdx.x >= gemm_blocks) {
        int e = ((int)blockIdx.x - gemm_blocks) * 256 + threadIdx.x;
        if (e >= E) return;
        const int src = ei[e];
        const int dst = ei[E + e];
        const float v0 = ps[2 * e]     * 4.0f;
        const float v1 = ps[2 * e + 1] * 4.0f;
        const float fb0 = floorf(v0), fb1 = floorf(v1);
        const float f0 = v0 - fb0, f1 = v1 - fb1;
        const int b0 = max(min((int)fb0, 4), 0);
        const int b1 = max(min((int)fb1, 4), 0);
        const u32 f0q = (u32)(f0 * 65536.0f);
        const u32 f1q = (u32)(f1 * 65536.0f);
        uint2 rec;
        rec.x = (u32)src | ((u32)b0 << 16) | ((u32)b1 << 19);
        rec.y = f0q | (f1q << 16);
        sorted[cursor[dst] + rank[e]] = rec;
        return;
    }
    gemm_body(X, Wb, XK, N, gr0, gr1, fp8out);
}

// ------------- layer-1 agg: fp8 spline gathers + bf16 root, width-4 + 2-deep pipeline -------------
// Quarter q = lane>>4 handles edge i+q, sublane j = lane&15 handles channels
// 4j..4j+3 (4 B fp8 gathers). Always relu.
__global__ __launch_bounds__(256) void agg_node_fp8(
    const uint2* __restrict__ sorted, const u32* __restrict__ cursor,
    const char* __restrict__ XK, const float* __restrict__ bias,
    float* __restrict__ out, int N)
{
    const int lane = threadIdx.x & 63;
    const int n = blockIdx.x * 4 + (threadIdx.x >> 6);
    if (n >= N) return;
    const int q = lane >> 4, j = lane & 15;
    const int beg = (int)cursor[n];
    const int end = (int)cursor[n + 1];

    float m0 = -INFINITY, m1 = -INFINITY, m2 = -INFINITY, m3 = -INFINITY;
    if (beg < end) {
        const int last = end - 1;
        uint2 rA = sorted[min(beg + q, last)];
        uint2 rB = sorted[min(beg + 4 + q, last)];
        const char* baseA = XK + (size_t)(rA.x & 0xffff) * ROWB1 + (j << 2);
        int oA = ((int)((rA.x >> 16) & 7) + 5 * (int)((rA.x >> 19) & 7)) << 6;
        u32 g0 = *(const u32*)(baseA + oA);
        u32 g1 = *(const u32*)(baseA + oA + 64);
        u32 g2 = *(const u32*)(baseA + oA + 320);
        u32 g3 = *(const u32*)(baseA + oA + 384);
        for (int i = beg; i < end; i += 4) {
            uint2 rC = sorted[min(i + 8 + q, last)];
            const char* baseB = XK + (size_t)(rB.x & 0xffff) * ROWB1 + (j << 2);
            int oB = ((int)((rB.x >> 16) & 7) + 5 * (int)((rB.x >> 19) & 7)) << 6;
            u32 h0 = *(const u32*)(baseB + oB);
            u32 h1 = *(const u32*)(baseB + oB + 64);
            u32 h2 = *(const u32*)(baseB + oB + 320);
            u32 h3 = *(const u32*)(baseB + oB + 384);
            const float f0 = (float)(rA.y & 0xffff) * (1.0f / 65536.0f);
            const float f1 = (float)(rA.y >> 16)    * (1.0f / 65536.0f);
            const float w00 = (1.f - f0) * (1.f - f1);
            const float w10 = f0 * (1.f - f1);
            const float w01 = (1.f - f0) * f1;
            const float w11 = f0 * f1;
            float v;
            v = fmaf(__builtin_amdgcn_cvt_f32_fp8(g3, 0), w11,
                fmaf(__builtin_amdgcn_cvt_f32_fp8(g2, 0), w01,
                fmaf(__builtin_amdgcn_cvt_f32_fp8(g1, 0), w10,
                     __builtin_amdgcn_cvt_f32_fp8(g0, 0) * w00)));
            m0 = fmaxf(m0, v);
            v = fmaf(__builtin_amdgcn_cvt_f32_fp8(g3, 1), w11,
                fmaf(__builtin_amdgcn_cvt_f32_fp8(g2, 1), w01,
                fmaf(__builtin_amdgcn_cvt_f32_fp8(g1, 1), w10,
                     __builtin_amdgcn_cvt_f32_fp8(g0, 1) * w00)));
            m1 = fmaxf(m1, v);
            v = fmaf(__builtin_amdgcn_cvt_f32_fp8(g3, 2), w11,
                fmaf(__builtin_amdgcn_cvt_f32_fp8(g2, 2), w01,
                fmaf(__builtin_amdgcn_cvt_f32_fp8(g1, 2), w10,
                     __builtin_amdgcn_cvt_f32_fp8(g0, 2) * w00)));
            m2 = fmaxf(m2, v);
            v = fmaf(__builtin_amdgcn_cvt_f32_fp8(g3, 3), w11,
                fmaf(__builtin_amdgcn_cvt_f32_fp8(g2, 3), w01,
                fmaf(__builtin_amdgcn_cvt_f32_fp8(g1, 3), w10,
                     __builtin_amdgcn_cvt_f32_fp8(g0, 3) * w00)));
            m3 = fmaxf(m3, v);
            rA = rB; rB = rC;
            g0 = h0; g1 = h1; g2 = h2; g3 = h3;
        }
    }
    m0 = fmaxf(m0, __shfl_xor(m0, 16, 64)); m0 = fmaxf(m0, __shfl_xor(m0, 32, 64));
    m1 = fmaxf(m1, __shfl_xor(m1, 16, 64)); m1 = fmaxf(m1, __shfl_xor(m1, 32, 64));
    m2 = fmaxf(m2, __shfl_xor(m2, 16, 64)); m2 = fmaxf(m2, __shfl_xor(m2, 32, 64));
    m3 = fmaxf(m3, __shfl_xor(m3, 16, 64)); m3 = fmaxf(m3, __shfl_xor(m3, 32, 64));
    const float a0 = isfinite(m0) ? m0 : 0.f;
    const float a1 = isfinite(m1) ? m1 : 0.f;
    const float a2 = isfinite(m2) ? m2 : 0.f;
    const float a3 = isfinite(m3) ? m3 : 0.f;

    const uint2 rt = *(const uint2*)(XK + (size_t)(unsigned)n * ROWB1 + 1600 + (j << 3));
    const float4 bv = *(const float4*)(bias + 4 * j);
    float r0 = fmaxf(a0 + blo(rt.x) + bv.x, 0.f);
    float r1 = fmaxf(a1 + bhi(rt.x) + bv.y, 0.f);
    float r2 = fmaxf(a2 + blo(rt.y) + bv.z, 0.f);
    float r3 = fmaxf(a3 + bhi(rt.y) + bv.w, 0.f);
    if (q == 0)
        *(float4*)(out + (size_t)n * CHANNELS + 4 * j) = make_float4(r0, r1, r2, r3);
}

// ------------- layer-2 agg: bf16 (R8-proven form), width-4 + 2-deep pipeline -------------
__global__ __launch_bounds__(256) void agg_node(
    const uint2* __restrict__ sorted, const u32* __restrict__ cursor,
    const char* __restrict__ XK, const float* __restrict__ bias,
    float* __restrict__ out, int N)
{
    const int lane = threadIdx.x & 63;
    const int n = blockIdx.x * 4 + (threadIdx.x >> 6);
    if (n >= N) return;
    const int q = lane >> 4, j = lane & 15;
    const int beg = (int)cursor[n];
    const int end = (int)cursor[n + 1];

    float m0 = -INFINITY, m1 = -INFINITY, m2 = -INFINITY, m3 = -INFINITY;
    if (beg < end) {
        const int last = end - 1;
        uint2 rA = sorted[min(beg + q, last)];
        uint2 rB = sorted[min(beg + 4 + q, last)];
        const char* baseA = XK + (size_t)(rA.x & 0xffff) * ROWB2 + (j << 3);
        int oA = ((int)((rA.x >> 16) & 7) + 5 * (int)((rA.x >> 19) & 7)) << 7;
        uint2 g0 = *(const uint2*)(baseA + oA);
        uint2 g1 = *(const uint2*)(baseA + oA + 128);
        uint2 g2 = *(const uint2*)(baseA + oA + 640);
        uint2 g3 = *(const uint2*)(baseA + oA + 768);
        for (int i = beg; i < end; i += 4) {
            uint2 rC = sorted[min(i + 8 + q, last)];
            const char* baseB = XK + (size_t)(rB.x & 0xffff) * ROWB2 + (j << 3);
            int oB = ((int)((rB.x >> 16) & 7) + 5 * (int)((rB.x >> 19) & 7)) << 7;
            uint2 h0 = *(const uint2*)(baseB + oB);
            uint2 h1 = *(const uint2*)(baseB + oB + 128);
            uint2 h2 = *(const uint2*)(baseB + oB + 640);
            uint2 h3 = *(const uint2*)(baseB + oB + 768);
            const float f0 = (float)(rA.y & 0xffff) * (1.0f / 65536.0f);
            const float f1 = (float)(rA.y >> 16)    * (1.0f / 65536.0f);
            const float w00 = (1.f - f0) * (1.f - f1);
            const float w10 = f0 * (1.f - f1);
            const float w01 = (1.f - f0) * f1;
            const float w11 = f0 * f1;
            float v0 = fmaf(blo(g3.x), w11, fmaf(blo(g2.x), w01, fmaf(blo(g1.x), w10, blo(g0.x) * w00)));
            float v1 = fmaf(bhi(g3.x), w11, fmaf(bhi(g2.x), w01, fmaf(bhi(g1.x), w10, bhi(g0.x) * w00)));
            float v2 = fmaf(blo(g3.y), w11, fmaf(blo(g2.y), w01, fmaf(blo(g1.y), w10, blo(g0.y) * w00)));
            float v3 = fmaf(bhi(g3.y), w11, fmaf(bhi(g2.y), w01, fmaf(bhi(g1.y), w10, bhi(g0.y) * w00)));
            m0 = fmaxf(m0, v0); m1 = fmaxf(m1, v1);
            m2 = fmaxf(m2, v2); m3 = fmaxf(m3, v3);
            rA = rB; rB = rC;
            g0 = h0; g1 = h1; g2 = h2; g3 = h3;
        }
    }
    m0 = fmaxf(m0, __shfl_xor(m0, 16, 64)); m0 = fmaxf(m0, __shfl_xor(m0, 32, 64));
    m1 = fmaxf(m1, __shfl_xor(m1, 16, 64)); m1 = fmaxf(m1, __shfl_xor(m1, 32, 64));
    m2 = fmaxf(m2, __shfl_xor(m2, 16, 64)); m2 = fmaxf(m2, __shfl_xor(m2, 32, 64));
    m3 = fmaxf(m3, __shfl_xor(m3, 16, 64)); m3 = fmaxf(m3, __shfl_xor(m3, 32, 64));
    const float a0 = isfinite(m0) ? m0 : 0.f;
    const float a1 = isfinite(m1) ? m1 : 0.f;
    const float a2 = isfinite(m2) ? m2 : 0.f;
    const float a3 = isfinite(m3) ? m3 : 0.f;

    const uint2 rt = *(const uint2*)(XK + (size_t)(unsigned)n * ROWB2 + KK * 128 + (j << 3));
    const float4 bv = *(const float4*)(bias + 4 * j);
    float r0 = a0 + blo(rt.x) + bv.x;
    float r1 = a1 + bhi(rt.x) + bv.y;
    float r2 = a2 + blo(rt.y) + bv.z;
    float r3 = a3 + bhi(rt.y) + bv.w;
    if (q == 0)
        *(float4*)(out + (size_t)n * CHANNELS + 4 * j) = make_float4(r0, r1, r2, r3);
}

extern "C" void kernel_launch(void* const* d_in, const int* in_sizes, int n_in,
                              void* d_out, int out_size, void* d_ws, size_t ws_size,
                              hipStream_t stream) {
    const float* x     = (const float*)d_in[0];
    const int*   ei    = (const int*)d_in[1];
    const float* ps    = (const float*)d_in[2];
    const float* W1    = (const float*)d_in[3];
    const float* root1 = (const float*)d_in[4];
    const float* bias1 = (const float*)d_in[5];
    const float* W2    = (const float*)d_in[6];
    const float* root2 = (const float*)d_in[7];
    const float* bias2 = (const float*)d_in[8];
    float* out = (float*)d_out;

    const int N = in_sizes[0] / CHANNELS;
    const int E = in_sizes[1] / 2;

    // ---- workspace layout (~199 MB) ----
    char* ws = (char*)d_ws;
    char* xk = ws;                                                  // N*3328 (L2 bf16); L1 fp8 uses same buffer at 1728 stride
    size_t off = (size_t)N * ROWB2;
    float* h = (float*)(ws + off);                                  // 12.8 MB
    off += (size_t)N * CHANNELS * sizeof(float);
    uint2* sorted = (uint2*)(ws + off);                             // E*8 = 12.8 MB
    off += (size_t)E * sizeof(uint2);
    u32* rank = (u32*)(ws + off);                                   // E*4 = 6.4 MB
    off += (size_t)E * sizeof(u32);
    u32* counts = (u32*)(ws + off);                                 // N*4 (hist runs under gemm)
    off += (size_t)N * 4;
    __hip_bfloat16* Wb = (__hip_bfloat16*)(ws + off);               // 213 KB
    off += (size_t)NTILES * 2 * 64 * 8 * 2;
    u32* cursor = (u32*)(ws + off);                                 // (N+1)*4
    off += ((size_t)N + 1) * 4;
    u32* bsum = (u32*)(ws + off);                                   // ≤4 KB

    const int prep_blocks = (NTILES * 2 * 64 * 8 + 255) / 256;
    const int gemm_blocks = (N + 63) / 64;
    const int node_blocks = (N + 3) / 4;
    const int edgeT_blocks = (E + 255) / 256;
    const int scan_blocks = (N + 1023) / 1024;

    // zero the histogram (capture-safe async memset)
    hipMemsetAsync(counts, 0, (size_t)N * 4, stream);
    prep_w<<<prep_blocks, 256, 0, stream>>>(W1, root1, Wb);

    // fusedA: L1 gemm groups [0,6) (fp8 xk) || dst-histogram with rank capture
    gemm_hist<<<gemm_blocks + edgeT_blocks, 256, 0, stream>>>(
        x, Wb, xk, N, gemm_blocks, 1, ei, counts, rank, E);

    scan_a<<<scan_blocks, 256, 0, stream>>>(counts, bsum, N);
    scan_b<<<1, 64, 0, stream>>>(bsum, scan_blocks);
    scan_c<<<scan_blocks, 256, 0, stream>>>(counts, bsum, cursor, N);

    // fusedB: L1 gemm groups [6,13) || CSR scatter (atomic-free)
    gemm_scatter<<<gemm_blocks + edgeT_blocks, 256, 0, stream>>>(
        x, Wb, xk, N, gemm_blocks, 1, ei, ps, rank, cursor, sorted, E, G_SPLIT, NGROUPS);
    agg_node_fp8<<<node_blocks, 256, 0, stream>>>(sorted, cursor, xk, bias1, h, N);

    // ---- layer 2 (bf16 xk) ----
    prep_w<<<prep_blocks, 256, 0, stream>>>(W2, root2, Wb);
    gemm_scatter<<<gemm_blocks, 256, 0, stream>>>(
        h, Wb, xk, N, gemm_blocks, 0, ei, ps, rank, cursor, sorted, 0, 0, NGROUPS);
    agg_node<<<node_blocks, 256, 0, stream>>>(sorted, cursor, xk, bias2, out, N);
}